// Round 2
// baseline (2241.160 us; speedup 1.0000x reference)
//
#include <hip/hip_runtime.h>
#include <math.h>

#define TT    2048
#define BKK   64
#define OBSD  64
#define NH    16
#define PDIM  64
#define NSTATE 64
#define DINN  1024
#define TB    (TT*BKK)   // 131072 rows

// ---------- DPP wave-64 sum (result valid in lane 63) ----------
template <int CTRL>
__device__ __forceinline__ float dpp_add(float x) {
    int y = __builtin_amdgcn_update_dpp(0, __float_as_int(x), CTRL, 0xF, 0xF, true);
    return x + __int_as_float(y);
}
__device__ __forceinline__ float wave_sum_lane63(float x) {
    x = dpp_add<0x111>(x);  // row_shr:1
    x = dpp_add<0x112>(x);  // row_shr:2
    x = dpp_add<0x114>(x);  // row_shr:4
    x = dpp_add<0x118>(x);  // row_shr:8  -> lane15 of each row16 = row sum
    x = dpp_add<0x142>(x);  // row_bcast:15
    x = dpp_add<0x143>(x);  // row_bcast:31 -> lane63 = full wave sum
    return x;
}

// ---------- zero the q half of d_out (harness poisons with 0xAA) ----------
__global__ void zero_q(float* __restrict__ q) {
    int i = blockIdx.x * 256 + threadIdx.x;
    if (i < TB) q[i] = 0.f;
}

// ---------- duplicate q -> logits ----------
__global__ void dup_q(float* __restrict__ q) {
    int i = blockIdx.x * 256 + threadIdx.x;
    if (i < TB) q[TB + i] = q[i];
}

// ---------- prelude: B = obs@W_B, C = obs@W_C, dt = softplus(r*Wdt+b), dec = exp(dt*A) ----------
// one wave handles 8 rows; lane = output column n
__global__ __launch_bounds__(256)
void prelude_kernel(const float* __restrict__ obs, const float* __restrict__ reward,
                    const float* __restrict__ WB, const float* __restrict__ WC,
                    const float* __restrict__ Wdt, const float* __restrict__ dtb,
                    const float* __restrict__ Alog,
                    float* __restrict__ Bws, float* __restrict__ Cws,
                    float* __restrict__ dtw, float* __restrict__ decw) {
    int gw = (blockIdx.x * 256 + threadIdx.x) >> 6;
    gw = __builtin_amdgcn_readfirstlane(gw);
    const int lane = threadIdx.x & 63;
    const int row0 = gw * 8;
    if (row0 >= TB) return;

    float aB[8], aC[8];
#pragma unroll
    for (int r = 0; r < 8; ++r) { aB[r] = 0.f; aC[r] = 0.f; }

#pragma unroll 8
    for (int kk = 0; kk < OBSD; ++kk) {
        float wb = WB[kk * 64 + lane];      // coalesced, L1-resident (16 KB)
        float wc = WC[kk * 64 + lane];
#pragma unroll
        for (int r = 0; r < 8; ++r) {
            float o = obs[(size_t)(row0 + r) * OBSD + kk];   // wave-uniform -> s_load
            aB[r] = fmaf(o, wb, aB[r]);
            aC[r] = fmaf(o, wc, aC[r]);
        }
    }
#pragma unroll
    for (int r = 0; r < 8; ++r) {
        Bws[(size_t)(row0 + r) * 64 + lane] = aB[r];
        Cws[(size_t)(row0 + r) * 64 + lane] = aC[r];
    }
    if (lane < NH) {
        float A    = -expf(Alog[lane]);
        float wdt  = Wdt[lane];
        float bias = dtb[lane];
#pragma unroll
        for (int r = 0; r < 8; ++r) {
            float rew = reward[row0 + r];
            float z = fmaf(rew, wdt, bias);
            float dt = (z > 20.f) ? z : log1pf(expf(z));   // softplus, overflow-safe
            dtw[(size_t)(row0 + r) * NH + lane]  = dt;
            decw[(size_t)(row0 + r) * NH + lane] = expf(dt * A);
        }
    }
}

// ---------- scan: one block (4 waves) per (b,h); wave w owns n-chunk, lane = p ----------
__global__ __launch_bounds__(256, 4)
void scan_kernel(const float* __restrict__ obs, const float* __restrict__ Win,
                 const float* __restrict__ Wout, const float* __restrict__ Dv,
                 const float* __restrict__ initS,
                 const float* __restrict__ Bws, const float* __restrict__ Cws,
                 const float* __restrict__ dtw, const float* __restrict__ decw,
                 float* __restrict__ qout) {
    __shared__ float upS[4 * 64];

    const int tid  = threadIdx.x;
    const int wu   = __builtin_amdgcn_readfirstlane(tid >> 6);  // wave 0..3 (n-chunk)
    const int lane = tid & 63;                                   // p
    const int bh   = blockIdx.x;                                 // 0..1023
    const int b    = bh & 63;
    const int h    = bh >> 6;
    const int n0   = wu * 16;

    // persistent per-lane state + W_in fragment
    float hh[16], win[16];
#pragma unroll
    for (int j = 0; j < 16; ++j) {
        hh[j]  = initS[h * PDIM * NSTATE + lane * NSTATE + n0 + j];
        win[j] = Win[(size_t)(n0 + j) * DINN + h * 64 + lane];
    }
    const float wp = Wout[h * 64 + lane];
    const float Dh = Dv[h];

#pragma unroll 1
    for (int t = 0; t < TT; ++t) {
        const int rb = t * BKK + b;   // uniform row index

        // --- fused u partial: this wave's 16-k slice of obs . Win[:,p] ---
        const float* op = obs + (size_t)rb * OBSD + n0;   // wave-uniform -> s_load
        float u0 = 0.f, u1 = 0.f;
#pragma unroll
        for (int j = 0; j < 16; j += 2) {
            u0 = fmaf(op[j],     win[j],     u0);
            u1 = fmaf(op[j + 1], win[j + 1], u1);
        }
        upS[wu * 64 + lane] = u0 + u1;
        __syncthreads();
        const float u = (upS[0 * 64 + lane] + upS[1 * 64 + lane]) +
                        (upS[2 * 64 + lane] + upS[3 * 64 + lane]);

        // --- uniform per-step scalars / chunks ---
        const float dtc = dtw[(size_t)rb * NH + h];
        const float dec = decw[(size_t)rb * NH + h];
        const float* Bp = Bws + (size_t)rb * 64 + n0;     // wave-uniform -> s_load
        const float* Cp = Cws + (size_t)rb * 64 + n0;

        // --- core: h = h*dec + (dt*u)*B ; s = sum h*C over this n-chunk ---
        const float x = dtc * u;
        float s0 = 0.f, s1 = 0.f;
#pragma unroll
        for (int j = 0; j < 16; j += 2) {
            hh[j]     = fmaf(hh[j],     dec, x * Bp[j]);
            hh[j + 1] = fmaf(hh[j + 1], dec, x * Bp[j + 1]);
            s0 = fmaf(hh[j],     Cp[j],     s0);
            s1 = fmaf(hh[j + 1], Cp[j + 1], s1);
        }
        float contrib = (s0 + s1) * wp;
        if (wu == 0) contrib = fmaf(Dh * u, wp, contrib);  // D*u term once per p

        // --- o = sum over (h,p,n-chunks): DPP wave sum + atomic across waves/blocks ---
        float tot = wave_sum_lane63(contrib);
        if (lane == 63) atomicAdd(qout + (size_t)t * BKK + b, tot);
        __syncthreads();   // protect upS before next iteration's writes
    }
}

extern "C" void kernel_launch(void* const* d_in, const int* in_sizes, int n_in,
                              void* d_out, int out_size, void* d_ws, size_t ws_size,
                              hipStream_t stream) {
    const float* obs    = (const float*)d_in[0];
    const float* reward = (const float*)d_in[1];
    const float* Win    = (const float*)d_in[2];
    const float* WB     = (const float*)d_in[3];
    const float* WC     = (const float*)d_in[4];
    const float* Wdt    = (const float*)d_in[5];
    const float* dtb    = (const float*)d_in[6];
    const float* Alog   = (const float*)d_in[7];
    const float* Dv     = (const float*)d_in[8];
    const float* Wout   = (const float*)d_in[9];
    const float* initS  = (const float*)d_in[10];
    float* qout = (float*)d_out;

    // workspace layout: B (33.5MB) | C (33.5MB) | dt (8.4MB) | dec (8.4MB)  ~= 84MB
    float* Bws  = (float*)d_ws;
    float* Cws  = Bws + (size_t)TB * 64;
    float* dtw  = Cws + (size_t)TB * 64;
    float* decw = dtw + (size_t)TB * NH;

    hipLaunchKernelGGL(zero_q,         dim3(TB / 256), dim3(256), 0, stream, qout);
    hipLaunchKernelGGL(prelude_kernel, dim3(TB / 32),  dim3(256), 0, stream,
                       obs, reward, WB, WC, Wdt, dtb, Alog, Bws, Cws, dtw, decw);
    hipLaunchKernelGGL(scan_kernel,    dim3(1024),     dim3(256), 0, stream,
                       obs, Win, Wout, Dv, initS, Bws, Cws, dtw, decw, qout);
    hipLaunchKernelGGL(dup_q,          dim3(TB / 256), dim3(256), 0, stream, qout);
}

// Round 6
// 2227.558 us; speedup vs baseline: 1.0061x; 1.0061x over previous
//
#include <hip/hip_runtime.h>
#include <math.h>

#define TT    2048
#define BKK   64
#define OBSD  64
#define NH    16
#define PDIM  64
#define NSTATE 64
#define DINN  1024
#define TB    (TT*BKK)   // 131072 rows

// ---------- DPP wave-64 sum (result valid in lane 63) ----------
template <int CTRL>
__device__ __forceinline__ float dpp_add(float x) {
    int y = __builtin_amdgcn_update_dpp(0, __float_as_int(x), CTRL, 0xF, 0xF, true);
    return x + __int_as_float(y);
}
__device__ __forceinline__ float wave_sum_lane63(float x) {
    x = dpp_add<0x111>(x);  // row_shr:1
    x = dpp_add<0x112>(x);  // row_shr:2
    x = dpp_add<0x114>(x);  // row_shr:4
    x = dpp_add<0x118>(x);  // row_shr:8  -> lane15 of each row16 = row sum
    x = dpp_add<0x142>(x);  // row_bcast:15
    x = dpp_add<0x143>(x);  // row_bcast:31 -> lane63 = full wave sum
    return x;
}

// ---------- zero the q half of d_out (harness poisons with 0xAA) ----------
__global__ void zero_q(float* __restrict__ q) {
    int i = blockIdx.x * 256 + threadIdx.x;
    if (i < TB) q[i] = 0.f;
}

// ---------- duplicate q -> logits ----------
__global__ void dup_q(float* __restrict__ q) {
    int i = blockIdx.x * 256 + threadIdx.x;
    if (i < TB) q[TB + i] = q[i];
}

// ---------- prelude: B = obs@W_B, C = obs@W_C, dd = {softplus dt, exp(dt*A)} interleaved ----------
__global__ __launch_bounds__(256)
void prelude_kernel(const float* __restrict__ obs, const float* __restrict__ reward,
                    const float* __restrict__ WB, const float* __restrict__ WC,
                    const float* __restrict__ Wdt, const float* __restrict__ dtb,
                    const float* __restrict__ Alog,
                    float* __restrict__ Bws, float* __restrict__ Cws,
                    float* __restrict__ ddws) {
    int gw = (blockIdx.x * 256 + threadIdx.x) >> 6;
    gw = __builtin_amdgcn_readfirstlane(gw);
    const int lane = threadIdx.x & 63;
    const int row0 = gw * 8;
    if (row0 >= TB) return;

    float aB[8], aC[8];
#pragma unroll
    for (int r = 0; r < 8; ++r) { aB[r] = 0.f; aC[r] = 0.f; }

#pragma unroll 8
    for (int kk = 0; kk < OBSD; ++kk) {
        float wb = WB[kk * 64 + lane];
        float wc = WC[kk * 64 + lane];
#pragma unroll
        for (int r = 0; r < 8; ++r) {
            float o = obs[(size_t)(row0 + r) * OBSD + kk];   // wave-uniform -> s_load
            aB[r] = fmaf(o, wb, aB[r]);
            aC[r] = fmaf(o, wc, aC[r]);
        }
    }
#pragma unroll
    for (int r = 0; r < 8; ++r) {
        Bws[(size_t)(row0 + r) * 64 + lane] = aB[r];
        Cws[(size_t)(row0 + r) * 64 + lane] = aC[r];
    }
    if (lane < NH) {
        float A    = -expf(Alog[lane]);
        float wdt  = Wdt[lane];
        float bias = dtb[lane];
#pragma unroll
        for (int r = 0; r < 8; ++r) {
            float rew = reward[row0 + r];
            float z = fmaf(rew, wdt, bias);
            float dt = (z > 20.f) ? z : log1pf(expf(z));
            ddws[(size_t)(row0 + r) * 32 + lane * 2 + 0] = dt;
            ddws[(size_t)(row0 + r) * 32 + lane * 2 + 1] = expf(dt * A);
        }
    }
}

// ---------- u = obs @ W_in : (TB,64)@(64,1024) fp32 ----------
// wave = 8 rows x 64-col chunk; lane = col within chunk
__global__ __launch_bounds__(256)
void u_gemm(const float* __restrict__ obs, const float* __restrict__ Win,
            float* __restrict__ u) {
    int wid = (blockIdx.x * 256 + threadIdx.x) >> 6;
    wid = __builtin_amdgcn_readfirstlane(wid);
    const int lane = threadIdx.x & 63;
    const int cc = wid & 15;          // col chunk of 64
    const int rg = wid >> 4;          // row group of 8
    const int r0 = rg * 8, c0 = cc * 64;
    if (r0 >= TB) return;

    float acc[8];
#pragma unroll
    for (int r = 0; r < 8; ++r) acc[r] = 0.f;

    const float* wcol = Win + c0 + lane;
    const float* orow = obs + (size_t)r0 * OBSD;
#pragma unroll 8
    for (int k = 0; k < OBSD; ++k) {
        float w = wcol[(size_t)k * DINN];           // per-lane, coalesced, L2-hit
#pragma unroll
        for (int r = 0; r < 8; ++r)
            acc[r] = fmaf(orow[r * OBSD + k], w, acc[r]);  // obs uniform -> s_load
    }
#pragma unroll
    for (int r = 0; r < 8; ++r)
        u[(size_t)(r0 + r) * DINN + c0 + lane] = acc[r];
}

// ---------- scan v2: wave = (h,b,nc); lane = p; zero LDS, zero barriers ----------
__global__ __launch_bounds__(256)
void scan2_kernel(const float* __restrict__ u, const float* __restrict__ Bws,
                  const float* __restrict__ Cws, const float* __restrict__ dd,
                  const float* __restrict__ Wout, const float* __restrict__ Dv,
                  const float* __restrict__ initS, float* __restrict__ qout) {
    int wid = blockIdx.x * 4 + (threadIdx.x >> 6);
    wid = __builtin_amdgcn_readfirstlane(wid);
    const int lane = threadIdx.x & 63;   // p
    const int nc = wid & 3;              // n-chunk
    const int b  = (wid >> 2) & 63;
    const int h  = wid >> 8;
    const int n0 = nc * 16;

    float hh[16];
#pragma unroll
    for (int j = 0; j < 16; ++j)
        hh[j] = initS[h * PDIM * NSTATE + lane * NSTATE + n0 + j];
    const float wp = Wout[h * 64 + lane];   // per-lane
    const float Dh = Dv[h];                 // uniform

    const float* up = u   + (size_t)b * DINN + h * 64;
    const float* Bp = Bws + (size_t)b * 64 + n0;
    const float* Cp = Cws + (size_t)b * 64 + n0;
    const float* dp = dd  + (size_t)b * 32 + h * 2;

    float* qb = qout + b;

    float uv = up[lane];   // prefetch t=0

#pragma unroll 2
    for (int t = 0; t < TT; ++t) {
        const float ucur = uv;
        // prefetch next step's u (vmcnt pipe, hidden under compute)
        const float* upn = up + (size_t)BKK * DINN;
        if (t < TT - 1) uv = upn[lane];

        const float dtc = dp[0];   // s_load_dwordx2
        const float dec = dp[1];

        const float x = dtc * ucur;
        float y0 = 0.f, y1 = 0.f;
#pragma unroll
        for (int j = 0; j < 16; j += 2) {
            hh[j]     = fmaf(hh[j],     dec, x * Bp[j]);
            y0 = fmaf(hh[j],     Cp[j],     y0);
            hh[j + 1] = fmaf(hh[j + 1], dec, x * Bp[j + 1]);
            y1 = fmaf(hh[j + 1], Cp[j + 1], y1);
        }
        float val = (y0 + y1) * wp;
        if (nc == 0) val = fmaf(Dh * ucur, wp, val);   // D*u term once per (b,h)

        float tot = wave_sum_lane63(val);
        if (lane == 63) atomicAdd(qb + (size_t)t * BKK, tot);

        up += (size_t)BKK * DINN;
        Bp += (size_t)BKK * 64;
        Cp += (size_t)BKK * 64;
        dp += (size_t)BKK * 32;
    }
}

// ---------- fallback scan (R2-style, fused u, LDS reduce) if ws too small ----------
__global__ __launch_bounds__(256, 4)
void scan_fb_kernel(const float* __restrict__ obs, const float* __restrict__ Win,
                    const float* __restrict__ Wout, const float* __restrict__ Dv,
                    const float* __restrict__ initS,
                    const float* __restrict__ Bws, const float* __restrict__ Cws,
                    const float* __restrict__ dd, float* __restrict__ qout) {
    __shared__ float upS[4 * 64];
    const int tid  = threadIdx.x;
    const int wu   = __builtin_amdgcn_readfirstlane(tid >> 6);
    const int lane = tid & 63;
    const int bh   = blockIdx.x;
    const int b    = bh & 63;
    const int h    = bh >> 6;
    const int n0   = wu * 16;

    float hh[16], win[16];
#pragma unroll
    for (int j = 0; j < 16; ++j) {
        hh[j]  = initS[h * PDIM * NSTATE + lane * NSTATE + n0 + j];
        win[j] = Win[(size_t)(n0 + j) * DINN + h * 64 + lane];
    }
    const float wp = Wout[h * 64 + lane];
    const float Dh = Dv[h];

#pragma unroll 1
    for (int t = 0; t < TT; ++t) {
        const int rb = t * BKK + b;
        const float* op = obs + (size_t)rb * OBSD + n0;
        float u0 = 0.f, u1 = 0.f;
#pragma unroll
        for (int j = 0; j < 16; j += 2) {
            u0 = fmaf(op[j],     win[j],     u0);
            u1 = fmaf(op[j + 1], win[j + 1], u1);
        }
        upS[wu * 64 + lane] = u0 + u1;
        __syncthreads();
        const float u = (upS[0 * 64 + lane] + upS[1 * 64 + lane]) +
                        (upS[2 * 64 + lane] + upS[3 * 64 + lane]);
        const float dtc = dd[(size_t)rb * 32 + h * 2 + 0];
        const float dec = dd[(size_t)rb * 32 + h * 2 + 1];
        const float* Bp = Bws + (size_t)rb * 64 + n0;
        const float* Cp = Cws + (size_t)rb * 64 + n0;
        const float x = dtc * u;
        float s0 = 0.f, s1 = 0.f;
#pragma unroll
        for (int j = 0; j < 16; j += 2) {
            hh[j]     = fmaf(hh[j],     dec, x * Bp[j]);
            hh[j + 1] = fmaf(hh[j + 1], dec, x * Bp[j + 1]);
            s0 = fmaf(hh[j],     Cp[j],     s0);
            s1 = fmaf(hh[j + 1], Cp[j + 1], s1);
        }
        float contrib = (s0 + s1) * wp;
        if (wu == 0) contrib = fmaf(Dh * u, wp, contrib);
        float tot = wave_sum_lane63(contrib);
        if (lane == 63) atomicAdd(qout + (size_t)t * BKK + b, tot);
        __syncthreads();
    }
}

extern "C" void kernel_launch(void* const* d_in, const int* in_sizes, int n_in,
                              void* d_out, int out_size, void* d_ws, size_t ws_size,
                              hipStream_t stream) {
    const float* obs    = (const float*)d_in[0];
    const float* reward = (const float*)d_in[1];
    const float* Win    = (const float*)d_in[2];
    const float* WB     = (const float*)d_in[3];
    const float* WC     = (const float*)d_in[4];
    const float* Wdt    = (const float*)d_in[5];
    const float* dtb    = (const float*)d_in[6];
    const float* Alog   = (const float*)d_in[7];
    const float* Dv     = (const float*)d_in[8];
    const float* Wout   = (const float*)d_in[9];
    const float* initS  = (const float*)d_in[10];
    float* qout = (float*)d_out;

    const size_t n_u  = (size_t)TB * DINN;   // 512 MiB
    const size_t n_B  = (size_t)TB * 64;     //  32 MiB
    const size_t n_dd = (size_t)TB * 32;     //  16 MiB
    const size_t need = (n_u + 2 * n_B + n_dd) * sizeof(float);  // 592 MiB

    if (ws_size >= need) {
        float* uws  = (float*)d_ws;
        float* Bws  = uws + n_u;
        float* Cws  = Bws + n_B;
        float* ddws = Cws + n_B;
        hipLaunchKernelGGL(zero_q,         dim3(TB / 256), dim3(256), 0, stream, qout);
        hipLaunchKernelGGL(prelude_kernel, dim3(TB / 32),  dim3(256), 0, stream,
                           obs, reward, WB, WC, Wdt, dtb, Alog, Bws, Cws, ddws);
        hipLaunchKernelGGL(u_gemm,         dim3(TB / 2),   dim3(256), 0, stream,
                           obs, Win, uws);   // 262144 waves total
        hipLaunchKernelGGL(scan2_kernel,   dim3(1024),     dim3(256), 0, stream,
                           uws, Bws, Cws, ddws, Wout, Dv, initS, qout);
        hipLaunchKernelGGL(dup_q,          dim3(TB / 256), dim3(256), 0, stream, qout);
    } else {
        float* Bws  = (float*)d_ws;
        float* Cws  = Bws + n_B;
        float* ddws = Cws + n_B;
        hipLaunchKernelGGL(zero_q,         dim3(TB / 256), dim3(256), 0, stream, qout);
        hipLaunchKernelGGL(prelude_kernel, dim3(TB / 32),  dim3(256), 0, stream,
                           obs, reward, WB, WC, Wdt, dtb, Alog, Bws, Cws, ddws);
        hipLaunchKernelGGL(scan_fb_kernel, dim3(1024),     dim3(256), 0, stream,
                           obs, Win, Wout, Dv, initS, Bws, Cws, ddws, qout);
        hipLaunchKernelGGL(dup_q,          dim3(TB / 256), dim3(256), 0, stream, qout);
    }
}

// Round 7
// 1382.349 us; speedup vs baseline: 1.6213x; 1.6114x over previous
//
#include <hip/hip_runtime.h>
#include <math.h>

#define TT     2048
#define BKK    64
#define OBSD   64
#define NH     16
#define PDIM   64
#define NSTATE 64
#define DINN   1024
#define TB     (TT*BKK)   // 131072 rows

// packed per-(t,b) row: [B(64) | C(64) | dec(16) | xw(16) | obase(1) | pad(3)]
#define RS      164
#define OFF_C   64
#define OFF_DEC 128
#define OFF_XW  144
#define OFF_OB  160

// ---------- DPP wave-64 sum (result valid in lane 63) ----------
template <int CTRL>
__device__ __forceinline__ float dpp_add(float x) {
    int y = __builtin_amdgcn_update_dpp(0, __float_as_int(x), CTRL, 0xF, 0xF, true);
    return x + __int_as_float(y);
}
__device__ __forceinline__ float wave_sum_lane63(float x) {
    x = dpp_add<0x111>(x);  // row_shr:1
    x = dpp_add<0x112>(x);  // row_shr:2
    x = dpp_add<0x114>(x);  // row_shr:4
    x = dpp_add<0x118>(x);  // row_shr:8
    x = dpp_add<0x142>(x);  // row_bcast:15
    x = dpp_add<0x143>(x);  // row_bcast:31 -> lane63 = full wave sum
    return x;
}

__device__ __forceinline__ float softplusf(float z) {
    return (z > 20.f) ? z : log1pf(expf(z));
}

// ---------- zero q (fallback path only; it uses atomics) ----------
__global__ void zero_q(float* __restrict__ q) {
    int i = blockIdx.x * 256 + threadIdx.x;
    if (i < TB) q[i] = 0.f;
}

// ---------- duplicate q -> logits ----------
__global__ void dup_q(float* __restrict__ q) {
    int i = blockIdx.x * 256 + threadIdx.x;
    if (i < TB) q[TB + i] = q[i];
}

// ---------- init: Wproj[64][16] and g0[16][64] ----------
// Wproj[k][h] = sum_p W_in[k, h*64+p] * Wout[h*64+p]
// g0[h][n]    = sum_p initS[h,p,n]    * Wout[h*64+p]
__global__ __launch_bounds__(1024)
void init_proj(const float* __restrict__ Win, const float* __restrict__ Wout,
               const float* __restrict__ initS,
               float* __restrict__ wproj, float* __restrict__ g0) {
    const int tid = threadIdx.x;
    {
        const int k = tid >> 4, h = tid & 15;
        float s = 0.f;
#pragma unroll 8
        for (int p = 0; p < PDIM; ++p)
            s = fmaf(Win[(size_t)k * DINN + h * 64 + p], Wout[h * 64 + p], s);
        wproj[tid] = s;   // layout [k][h] = k*16+h = tid
    }
    {
        const int h = tid >> 6, n = tid & 63;
        float s = 0.f;
#pragma unroll 8
        for (int p = 0; p < PDIM; ++p)
            s = fmaf(initS[h * PDIM * NSTATE + p * NSTATE + n], Wout[h * 64 + p], s);
        g0[tid] = s;      // layout [h][n] = h*64+n = tid
    }
}

// ---------- prelude2: build packed rows ----------
// wave = 8 rows; lane: h = lane&15, q = lane>>4 (k-quarter)
__global__ __launch_bounds__(256)
void prelude2(const float* __restrict__ obs, const float* __restrict__ reward,
              const float* __restrict__ WB, const float* __restrict__ WC,
              const float* __restrict__ Wdt, const float* __restrict__ dtb,
              const float* __restrict__ Alog, const float* __restrict__ Dv,
              const float* __restrict__ wproj, float* __restrict__ rows) {
    int gw = (blockIdx.x * 256 + threadIdx.x) >> 6;
    gw = __builtin_amdgcn_readfirstlane(gw);
    const int lane = threadIdx.x & 63;
    const int row0 = gw * 8;
    if (row0 >= TB) return;

    const int h = lane & 15;
    const int q = lane >> 4;

    // hoisted per-lane tables
    const float wdt_h = Wdt[h];
    const float dtb_h = dtb[h];
    const float A_h   = -expf(Alog[h]);
    const float D_h   = Dv[h];
    float wpj[16];
#pragma unroll
    for (int j = 0; j < 16; ++j)
        wpj[j] = wproj[(q * 16 + j) * 16 + h];

    // B/C projections (obs uniform s_load, WB/WC per-lane)
    float aB[8], aC[8];
#pragma unroll
    for (int r = 0; r < 8; ++r) { aB[r] = 0.f; aC[r] = 0.f; }
#pragma unroll 8
    for (int kk = 0; kk < OBSD; ++kk) {
        float wb = WB[kk * 64 + lane];
        float wc = WC[kk * 64 + lane];
#pragma unroll
        for (int r = 0; r < 8; ++r) {
            float o = obs[(size_t)(row0 + r) * OBSD + kk];
            aB[r] = fmaf(o, wb, aB[r]);
            aC[r] = fmaf(o, wc, aC[r]);
        }
    }

#pragma unroll 1
    for (int r = 0; r < 8; ++r) {
        const int row = row0 + r;
        float* rb = rows + (size_t)row * RS;
        rb[lane]         = aB[r];
        rb[OFF_C + lane] = aC[r];

        // w[h] partial over this lane's k-quarter
        const float4* oq = (const float4*)(obs + (size_t)row * OBSD + q * 16);
        float4 o0 = oq[0], o1 = oq[1], o2 = oq[2], o3 = oq[3];
        float wpart = 0.f;
        wpart = fmaf(o0.x, wpj[0],  wpart); wpart = fmaf(o0.y, wpj[1],  wpart);
        wpart = fmaf(o0.z, wpj[2],  wpart); wpart = fmaf(o0.w, wpj[3],  wpart);
        wpart = fmaf(o1.x, wpj[4],  wpart); wpart = fmaf(o1.y, wpj[5],  wpart);
        wpart = fmaf(o1.z, wpj[6],  wpart); wpart = fmaf(o1.w, wpj[7],  wpart);
        wpart = fmaf(o2.x, wpj[8],  wpart); wpart = fmaf(o2.y, wpj[9],  wpart);
        wpart = fmaf(o2.z, wpj[10], wpart); wpart = fmaf(o2.w, wpj[11], wpart);
        wpart = fmaf(o3.x, wpj[12], wpart); wpart = fmaf(o3.y, wpj[13], wpart);
        wpart = fmaf(o3.z, wpj[14], wpart); wpart = fmaf(o3.w, wpj[15], wpart);
        // reduce quarters: every lane ends with w[h]
        wpart += __shfl_xor(wpart, 16, 64);
        wpart += __shfl_xor(wpart, 32, 64);

        const float rew  = reward[row];                     // uniform
        const float dtv  = softplusf(fmaf(rew, wdt_h, dtb_h));
        const float decv = expf(dtv * A_h);
        const float xwv  = dtv * wpart;
        if (q == 0) rb[OFF_DEC + h] = decv;
        if (q == 1) rb[OFF_XW  + h] = xwv;

        // obase = sum_h D[h]*w[h] (reduce within each 16-lane group)
        float dw = D_h * wpart;
        dw += __shfl_xor(dw, 1, 64);
        dw += __shfl_xor(dw, 2, 64);
        dw += __shfl_xor(dw, 4, 64);
        dw += __shfl_xor(dw, 8, 64);
        if (lane == 0) rb[OFF_OB] = dw;
    }
}

// ---------- scan3: 1 wave per b; lane = n; state g[16] (h) ----------
__global__ __launch_bounds__(64)
void scan3_kernel(const float* __restrict__ rows, const float* __restrict__ g0,
                  float* __restrict__ qout) {
    const int b    = blockIdx.x;
    const int lane = threadIdx.x;   // n

    float g[16];
#pragma unroll
    for (int hh = 0; hh < 16; ++hh)
        g[hh] = g0[hh * 64 + lane];

    const float* rowp = rows + (size_t)b * RS;
    float Bv = rowp[lane];
    float Cv = rowp[OFF_C + lane];

#pragma unroll 2
    for (int t = 0; t < TT; ++t) {
        const float* nrow = rowp + (size_t)RS * BKK;
        float Bn = 0.f, Cn = 0.f;
        if (t < TT - 1) { Bn = nrow[lane]; Cn = nrow[OFF_C + lane]; }  // vmcnt prefetch

        float y = 0.f;
#pragma unroll
        for (int hh = 0; hh < 16; ++hh) {
            float tmp = rowp[OFF_XW + hh] * Bv;          // uniform s_load
            g[hh] = fmaf(g[hh], rowp[OFF_DEC + hh], tmp);
            y = fmaf(g[hh], Cv, y);
        }
        const float ob = rowp[OFF_OB];

        float tot = wave_sum_lane63(y);
        if (lane == 63) qout[(size_t)t * BKK + b] = tot + ob;

        rowp = nrow; Bv = Bn; Cv = Cn;
    }
}

// ---------- fallback (proven R6 path, ~84 MB ws) ----------
__global__ __launch_bounds__(256)
void prelude_kernel(const float* __restrict__ obs, const float* __restrict__ reward,
                    const float* __restrict__ WB, const float* __restrict__ WC,
                    const float* __restrict__ Wdt, const float* __restrict__ dtb,
                    const float* __restrict__ Alog,
                    float* __restrict__ Bws, float* __restrict__ Cws,
                    float* __restrict__ ddws) {
    int gw = (blockIdx.x * 256 + threadIdx.x) >> 6;
    gw = __builtin_amdgcn_readfirstlane(gw);
    const int lane = threadIdx.x & 63;
    const int row0 = gw * 8;
    if (row0 >= TB) return;

    float aB[8], aC[8];
#pragma unroll
    for (int r = 0; r < 8; ++r) { aB[r] = 0.f; aC[r] = 0.f; }
#pragma unroll 8
    for (int kk = 0; kk < OBSD; ++kk) {
        float wb = WB[kk * 64 + lane];
        float wc = WC[kk * 64 + lane];
#pragma unroll
        for (int r = 0; r < 8; ++r) {
            float o = obs[(size_t)(row0 + r) * OBSD + kk];
            aB[r] = fmaf(o, wb, aB[r]);
            aC[r] = fmaf(o, wc, aC[r]);
        }
    }
#pragma unroll
    for (int r = 0; r < 8; ++r) {
        Bws[(size_t)(row0 + r) * 64 + lane] = aB[r];
        Cws[(size_t)(row0 + r) * 64 + lane] = aC[r];
    }
    if (lane < NH) {
        float A    = -expf(Alog[lane]);
        float wdt  = Wdt[lane];
        float bias = dtb[lane];
#pragma unroll
        for (int r = 0; r < 8; ++r) {
            float rew = reward[row0 + r];
            float dt = softplusf(fmaf(rew, wdt, bias));
            ddws[(size_t)(row0 + r) * 32 + lane * 2 + 0] = dt;
            ddws[(size_t)(row0 + r) * 32 + lane * 2 + 1] = expf(dt * A);
        }
    }
}

__global__ __launch_bounds__(256, 4)
void scan_fb_kernel(const float* __restrict__ obs, const float* __restrict__ Win,
                    const float* __restrict__ Wout, const float* __restrict__ Dv,
                    const float* __restrict__ initS,
                    const float* __restrict__ Bws, const float* __restrict__ Cws,
                    const float* __restrict__ dd, float* __restrict__ qout) {
    __shared__ float upS[4 * 64];
    const int tid  = threadIdx.x;
    const int wu   = __builtin_amdgcn_readfirstlane(tid >> 6);
    const int lane = tid & 63;
    const int bh   = blockIdx.x;
    const int b    = bh & 63;
    const int h    = bh >> 6;
    const int n0   = wu * 16;

    float hh[16], win[16];
#pragma unroll
    for (int j = 0; j < 16; ++j) {
        hh[j]  = initS[h * PDIM * NSTATE + lane * NSTATE + n0 + j];
        win[j] = Win[(size_t)(n0 + j) * DINN + h * 64 + lane];
    }
    const float wp = Wout[h * 64 + lane];
    const float Dh = Dv[h];

#pragma unroll 1
    for (int t = 0; t < TT; ++t) {
        const int rb = t * BKK + b;
        const float* op = obs + (size_t)rb * OBSD + n0;
        float u0 = 0.f, u1 = 0.f;
#pragma unroll
        for (int j = 0; j < 16; j += 2) {
            u0 = fmaf(op[j],     win[j],     u0);
            u1 = fmaf(op[j + 1], win[j + 1], u1);
        }
        upS[wu * 64 + lane] = u0 + u1;
        __syncthreads();
        const float u = (upS[0 * 64 + lane] + upS[1 * 64 + lane]) +
                        (upS[2 * 64 + lane] + upS[3 * 64 + lane]);
        const float dtc = dd[(size_t)rb * 32 + h * 2 + 0];
        const float dec = dd[(size_t)rb * 32 + h * 2 + 1];
        const float* Bp = Bws + (size_t)rb * 64 + n0;
        const float* Cp = Cws + (size_t)rb * 64 + n0;
        const float x = dtc * u;
        float s0 = 0.f, s1 = 0.f;
#pragma unroll
        for (int j = 0; j < 16; j += 2) {
            hh[j]     = fmaf(hh[j],     dec, x * Bp[j]);
            hh[j + 1] = fmaf(hh[j + 1], dec, x * Bp[j + 1]);
            s0 = fmaf(hh[j],     Cp[j],     s0);
            s1 = fmaf(hh[j + 1], Cp[j + 1], s1);
        }
        float contrib = (s0 + s1) * wp;
        if (wu == 0) contrib = fmaf(Dh * u, wp, contrib);
        float tot = wave_sum_lane63(contrib);
        if (lane == 63) atomicAdd(qout + (size_t)t * BKK + b, tot);
        __syncthreads();
    }
}

extern "C" void kernel_launch(void* const* d_in, const int* in_sizes, int n_in,
                              void* d_out, int out_size, void* d_ws, size_t ws_size,
                              hipStream_t stream) {
    const float* obs    = (const float*)d_in[0];
    const float* reward = (const float*)d_in[1];
    const float* Win    = (const float*)d_in[2];
    const float* WB     = (const float*)d_in[3];
    const float* WC     = (const float*)d_in[4];
    const float* Wdt    = (const float*)d_in[5];
    const float* dtb    = (const float*)d_in[6];
    const float* Alog   = (const float*)d_in[7];
    const float* Dv     = (const float*)d_in[8];
    const float* Wout   = (const float*)d_in[9];
    const float* initS  = (const float*)d_in[10];
    float* qout = (float*)d_out;

    const size_t n_rows = (size_t)TB * RS;                 // 21.5 M floats
    const size_t need   = (n_rows + 1024 + 1024) * 4;      // ~86.0 MB

    if (ws_size >= need) {
        float* rows  = (float*)d_ws;
        float* wproj = rows + n_rows;
        float* g0    = wproj + 1024;
        hipLaunchKernelGGL(init_proj, dim3(1),       dim3(1024), 0, stream,
                           Win, Wout, initS, wproj, g0);
        hipLaunchKernelGGL(prelude2,  dim3(TB / 32), dim3(256),  0, stream,
                           obs, reward, WB, WC, Wdt, dtb, Alog, Dv, wproj, rows);
        hipLaunchKernelGGL(scan3_kernel, dim3(BKK),  dim3(64),   0, stream,
                           rows, g0, qout);
        hipLaunchKernelGGL(dup_q,     dim3(TB / 256), dim3(256), 0, stream, qout);
    } else {
        const size_t n_B  = (size_t)TB * 64;
        float* Bws  = (float*)d_ws;
        float* Cws  = Bws + n_B;
        float* ddws = Cws + n_B;
        hipLaunchKernelGGL(zero_q,         dim3(TB / 256), dim3(256), 0, stream, qout);
        hipLaunchKernelGGL(prelude_kernel, dim3(TB / 32),  dim3(256), 0, stream,
                           obs, reward, WB, WC, Wdt, dtb, Alog, Bws, Cws, ddws);
        hipLaunchKernelGGL(scan_fb_kernel, dim3(1024),     dim3(256), 0, stream,
                           obs, Win, Wout, Dv, initS, Bws, Cws, ddws, qout);
        hipLaunchKernelGGL(dup_q,          dim3(TB / 256), dim3(256), 0, stream, qout);
    }
}

// Round 8
// 256.089 us; speedup vs baseline: 8.7515x; 5.3979x over previous
//
#include <hip/hip_runtime.h>
#include <math.h>

#define TT     2048
#define BKK    64
#define OBSD   64
#define NH     16
#define PDIM   64
#define NSTATE 64
#define DINN   1024
#define TB     (TT*BKK)   // 131072 rows
#define NC     32         // chunks over T
#define CL     (TT/NC)    // 64 steps per chunk

// packed per-(t,b) row: [B(64) | C(64) | dec(16) | xw(16) | obase(1) | pad(3)]
#define RS      164
#define OFF_C   64
#define OFF_DEC 128
#define OFF_XW  144
#define OFF_OB  160

// ---------- DPP wave-64 sum (result valid in lane 63) ----------
template <int CTRL>
__device__ __forceinline__ float dpp_add(float x) {
    int y = __builtin_amdgcn_update_dpp(0, __float_as_int(x), CTRL, 0xF, 0xF, true);
    return x + __int_as_float(y);
}
__device__ __forceinline__ float wave_sum_lane63(float x) {
    x = dpp_add<0x111>(x);
    x = dpp_add<0x112>(x);
    x = dpp_add<0x114>(x);
    x = dpp_add<0x118>(x);
    x = dpp_add<0x142>(x);
    x = dpp_add<0x143>(x);
    return x;
}

__device__ __forceinline__ float softplusf(float z) {
    return (z > 20.f) ? z : log1pf(expf(z));
}

// ---------- duplicate q -> logits ----------
__global__ void dup_q(float* __restrict__ q) {
    int i = blockIdx.x * 256 + threadIdx.x;
    if (i < TB) q[TB + i] = q[i];
}

// ---------- init: Wproj[64][16] and g0[16][64] ----------
__global__ __launch_bounds__(1024)
void init_proj(const float* __restrict__ Win, const float* __restrict__ Wout,
               const float* __restrict__ initS,
               float* __restrict__ wproj, float* __restrict__ g0) {
    const int tid = threadIdx.x;
    {
        const int k = tid >> 4, h = tid & 15;
        float s = 0.f;
#pragma unroll 8
        for (int p = 0; p < PDIM; ++p)
            s = fmaf(Win[(size_t)k * DINN + h * 64 + p], Wout[h * 64 + p], s);
        wproj[tid] = s;   // [k][h]
    }
    {
        const int h = tid >> 6, n = tid & 63;
        float s = 0.f;
#pragma unroll 8
        for (int p = 0; p < PDIM; ++p)
            s = fmaf(initS[h * PDIM * NSTATE + p * NSTATE + n], Wout[h * 64 + p], s);
        g0[tid] = s;      // [h][n]
    }
}

// ---------- prelude2: build packed rows (unchanged from R7, validated) ----------
__global__ __launch_bounds__(256)
void prelude2(const float* __restrict__ obs, const float* __restrict__ reward,
              const float* __restrict__ WB, const float* __restrict__ WC,
              const float* __restrict__ Wdt, const float* __restrict__ dtb,
              const float* __restrict__ Alog, const float* __restrict__ Dv,
              const float* __restrict__ wproj, float* __restrict__ rows) {
    int gw = (blockIdx.x * 256 + threadIdx.x) >> 6;
    gw = __builtin_amdgcn_readfirstlane(gw);
    const int lane = threadIdx.x & 63;
    const int row0 = gw * 8;
    if (row0 >= TB) return;

    const int h = lane & 15;
    const int q = lane >> 4;

    const float wdt_h = Wdt[h];
    const float dtb_h = dtb[h];
    const float A_h   = -expf(Alog[h]);
    const float D_h   = Dv[h];
    float wpj[16];
#pragma unroll
    for (int j = 0; j < 16; ++j)
        wpj[j] = wproj[(q * 16 + j) * 16 + h];

    float aB[8], aC[8];
#pragma unroll
    for (int r = 0; r < 8; ++r) { aB[r] = 0.f; aC[r] = 0.f; }
#pragma unroll 8
    for (int kk = 0; kk < OBSD; ++kk) {
        float wb = WB[kk * 64 + lane];
        float wc = WC[kk * 64 + lane];
#pragma unroll
        for (int r = 0; r < 8; ++r) {
            float o = obs[(size_t)(row0 + r) * OBSD + kk];
            aB[r] = fmaf(o, wb, aB[r]);
            aC[r] = fmaf(o, wc, aC[r]);
        }
    }

#pragma unroll 1
    for (int r = 0; r < 8; ++r) {
        const int row = row0 + r;
        float* rb = rows + (size_t)row * RS;
        rb[lane]         = aB[r];
        rb[OFF_C + lane] = aC[r];

        const float4* oq = (const float4*)(obs + (size_t)row * OBSD + q * 16);
        float4 o0 = oq[0], o1 = oq[1], o2 = oq[2], o3 = oq[3];
        float wpart = 0.f;
        wpart = fmaf(o0.x, wpj[0],  wpart); wpart = fmaf(o0.y, wpj[1],  wpart);
        wpart = fmaf(o0.z, wpj[2],  wpart); wpart = fmaf(o0.w, wpj[3],  wpart);
        wpart = fmaf(o1.x, wpj[4],  wpart); wpart = fmaf(o1.y, wpj[5],  wpart);
        wpart = fmaf(o1.z, wpj[6],  wpart); wpart = fmaf(o1.w, wpj[7],  wpart);
        wpart = fmaf(o2.x, wpj[8],  wpart); wpart = fmaf(o2.y, wpj[9],  wpart);
        wpart = fmaf(o2.z, wpj[10], wpart); wpart = fmaf(o2.w, wpj[11], wpart);
        wpart = fmaf(o3.x, wpj[12], wpart); wpart = fmaf(o3.y, wpj[13], wpart);
        wpart = fmaf(o3.z, wpj[14], wpart); wpart = fmaf(o3.w, wpj[15], wpart);
        wpart += __shfl_xor(wpart, 16, 64);
        wpart += __shfl_xor(wpart, 32, 64);

        const float rew  = reward[row];
        const float dtv  = softplusf(fmaf(rew, wdt_h, dtb_h));
        const float decv = expf(dtv * A_h);
        const float xwv  = dtv * wpart;
        if (q == 0) rb[OFF_DEC + h] = decv;
        if (q == 1) rb[OFF_XW  + h] = xwv;

        float dw = D_h * wpart;
        dw += __shfl_xor(dw, 1, 64);
        dw += __shfl_xor(dw, 2, 64);
        dw += __shfl_xor(dw, 4, 64);
        dw += __shfl_xor(dw, 8, 64);
        if (lane == 0) rb[OFF_OB] = dw;
    }
}

// ---------- phase A: per-(b,c) zero-init chunk scan -> Send, Ptot ----------
__global__ __launch_bounds__(256)
void phaseA(const float* __restrict__ rows, float* __restrict__ Send,
            float* __restrict__ Ptot) {
    int w = (blockIdx.x * 256 + threadIdx.x) >> 6;   // 0..2047
    w = __builtin_amdgcn_readfirstlane(w);
    const int lane = threadIdx.x & 63;   // n
    const int b = w & 63;
    const int c = w >> 6;

    const float* rowp = rows + ((size_t)(c * CL) * BKK + b) * RS;
    float g[16], Pc[16];
#pragma unroll
    for (int hh = 0; hh < 16; ++hh) { g[hh] = 0.f; Pc[hh] = 1.f; }

    float Bv = rowp[lane];

#pragma unroll 2
    for (int i = 0; i < CL; ++i) {
        const float* nxt = rowp + (size_t)RS * BKK;
        float Bn = 0.f;
        if (i < CL - 1) Bn = nxt[lane];
#pragma unroll
        for (int hh = 0; hh < 16; ++hh) {
            const float dh = rowp[OFF_DEC + hh];
            g[hh] = fmaf(g[hh], dh, rowp[OFF_XW + hh] * Bv);
            Pc[hh] *= dh;
        }
        rowp = nxt; Bv = Bn;
    }

    const size_t base = ((size_t)c * BKK + b) * 16;
#pragma unroll
    for (int hh = 0; hh < 16; ++hh)
        Send[(base + hh) * 64 + lane] = g[hh];
    if (lane == 0) {
#pragma unroll
        for (int hh = 0; hh < 16; ++hh)
            Ptot[base + hh] = Pc[hh];
    }
}

// ---------- phase B: serial scan over 32 chunk states (per b) ----------
__global__ __launch_bounds__(64)
void phaseB(const float* __restrict__ g0, const float* __restrict__ Send,
            const float* __restrict__ Ptot, float* __restrict__ gcbuf) {
    const int b    = blockIdx.x;
    const int lane = threadIdx.x;   // n

    float g[16];
#pragma unroll
    for (int hh = 0; hh < 16; ++hh)
        g[hh] = g0[hh * 64 + lane];

#pragma unroll 1
    for (int c = 0; c < NC; ++c) {
        const size_t base = ((size_t)c * BKK + b) * 16;
#pragma unroll
        for (int hh = 0; hh < 16; ++hh)
            gcbuf[(base + hh) * 64 + lane] = g[hh];
        if (c < NC - 1) {
#pragma unroll
            for (int hh = 0; hh < 16; ++hh)
                g[hh] = fmaf(Ptot[base + hh], g[hh], Send[(base + hh) * 64 + lane]);
        }
    }
}

// ---------- phase C: per-(b,c) seeded chunk scan -> q ----------
__global__ __launch_bounds__(256)
void phaseC(const float* __restrict__ rows, const float* __restrict__ gcbuf,
            float* __restrict__ qout) {
    int w = (blockIdx.x * 256 + threadIdx.x) >> 6;   // 0..2047
    w = __builtin_amdgcn_readfirstlane(w);
    const int lane = threadIdx.x & 63;   // n
    const int b = w & 63;
    const int c = w >> 6;

    const size_t base = ((size_t)c * BKK + b) * 16;
    float g[16];
#pragma unroll
    for (int hh = 0; hh < 16; ++hh)
        g[hh] = gcbuf[(base + hh) * 64 + lane];

    const float* rowp = rows + ((size_t)(c * CL) * BKK + b) * RS;
    float Bv = rowp[lane];
    float Cv = rowp[OFF_C + lane];

#pragma unroll 2
    for (int i = 0; i < CL; ++i) {
        const float* nxt = rowp + (size_t)RS * BKK;
        float Bn = 0.f, Cn = 0.f;
        if (i < CL - 1) { Bn = nxt[lane]; Cn = nxt[OFF_C + lane]; }

        float y = 0.f;
#pragma unroll
        for (int hh = 0; hh < 16; ++hh) {
            g[hh] = fmaf(g[hh], rowp[OFF_DEC + hh], rowp[OFF_XW + hh] * Bv);
            y = fmaf(g[hh], Cv, y);
        }
        const float ob = rowp[OFF_OB];

        float tot = wave_sum_lane63(y);
        if (lane == 63) qout[(size_t)(c * CL + i) * BKK + b] = tot + ob;

        rowp = nxt; Bv = Bn; Cv = Cn;
    }
}

// ---------- mid-tier: scan3 (R7 path, validated) ----------
__global__ __launch_bounds__(64)
void scan3_kernel(const float* __restrict__ rows, const float* __restrict__ g0,
                  float* __restrict__ qout) {
    const int b    = blockIdx.x;
    const int lane = threadIdx.x;   // n

    float g[16];
#pragma unroll
    for (int hh = 0; hh < 16; ++hh)
        g[hh] = g0[hh * 64 + lane];

    const float* rowp = rows + (size_t)b * RS;
    float Bv = rowp[lane];
    float Cv = rowp[OFF_C + lane];

#pragma unroll 2
    for (int t = 0; t < TT; ++t) {
        const float* nrow = rowp + (size_t)RS * BKK;
        float Bn = 0.f, Cn = 0.f;
        if (t < TT - 1) { Bn = nrow[lane]; Cn = nrow[OFF_C + lane]; }

        float y = 0.f;
#pragma unroll
        for (int hh = 0; hh < 16; ++hh) {
            float tmp = rowp[OFF_XW + hh] * Bv;
            g[hh] = fmaf(g[hh], rowp[OFF_DEC + hh], tmp);
            y = fmaf(g[hh], Cv, y);
        }
        const float ob = rowp[OFF_OB];

        float tot = wave_sum_lane63(y);
        if (lane == 63) qout[(size_t)t * BKK + b] = tot + ob;

        rowp = nrow; Bv = Bn; Cv = Cn;
    }
}

extern "C" void kernel_launch(void* const* d_in, const int* in_sizes, int n_in,
                              void* d_out, int out_size, void* d_ws, size_t ws_size,
                              hipStream_t stream) {
    const float* obs    = (const float*)d_in[0];
    const float* reward = (const float*)d_in[1];
    const float* Win    = (const float*)d_in[2];
    const float* WB     = (const float*)d_in[3];
    const float* WC     = (const float*)d_in[4];
    const float* Wdt    = (const float*)d_in[5];
    const float* dtb    = (const float*)d_in[6];
    const float* Alog   = (const float*)d_in[7];
    const float* Dv     = (const float*)d_in[8];
    const float* Wout   = (const float*)d_in[9];
    const float* initS  = (const float*)d_in[10];
    float* qout = (float*)d_out;

    const size_t n_rows = (size_t)TB * RS;           // 21.5 M floats
    const size_t n_cs   = (size_t)NC * BKK * 16 * 64; // 2.1 M floats (Send / gcbuf)
    const size_t n_pt   = (size_t)NC * BKK * 16;      // 32 K floats

    const size_t need1 = (n_rows + 2048) * 4;                     // ~86.0 MB
    const size_t need2 = (n_rows + 2048 + 2 * n_cs + n_pt) * 4;   // ~102.9 MB

    float* rows  = (float*)d_ws;
    float* wproj = rows + n_rows;
    float* g0    = wproj + 1024;

    if (ws_size >= need2) {
        float* Send  = g0 + 1024;
        float* gcbuf = Send + n_cs;
        float* Ptot  = gcbuf + n_cs;
        hipLaunchKernelGGL(init_proj, dim3(1),        dim3(1024), 0, stream,
                           Win, Wout, initS, wproj, g0);
        hipLaunchKernelGGL(prelude2,  dim3(TB / 32),  dim3(256),  0, stream,
                           obs, reward, WB, WC, Wdt, dtb, Alog, Dv, wproj, rows);
        hipLaunchKernelGGL(phaseA,    dim3(512),      dim3(256),  0, stream,
                           rows, Send, Ptot);
        hipLaunchKernelGGL(phaseB,    dim3(BKK),      dim3(64),   0, stream,
                           g0, Send, Ptot, gcbuf);
        hipLaunchKernelGGL(phaseC,    dim3(512),      dim3(256),  0, stream,
                           rows, gcbuf, qout);
        hipLaunchKernelGGL(dup_q,     dim3(TB / 256), dim3(256),  0, stream, qout);
    } else {
        // proven R7 path (ws >= 86 MB confirmed on this harness)
        hipLaunchKernelGGL(init_proj, dim3(1),        dim3(1024), 0, stream,
                           Win, Wout, initS, wproj, g0);
        hipLaunchKernelGGL(prelude2,  dim3(TB / 32),  dim3(256),  0, stream,
                           obs, reward, WB, WC, Wdt, dtb, Alog, Dv, wproj, rows);
        hipLaunchKernelGGL(scan3_kernel, dim3(BKK),   dim3(64),   0, stream,
                           rows, g0, qout);
        hipLaunchKernelGGL(dup_q,     dim3(TB / 256), dim3(256),  0, stream, qout);
    }
}

// Round 9
// 234.711 us; speedup vs baseline: 9.5486x; 1.0911x over previous
//
#include <hip/hip_runtime.h>
#include <math.h>

#define TT     2048
#define BKK    64
#define OBSD   64
#define NH     16
#define PDIM   64
#define NSTATE 64
#define DINN   1024
#define TB     (TT*BKK)   // 131072 rows

// packed per-(t,b) row: [B(64) | C(64) | dec(16) | xw(16) | obase(1) | pad(3)]
#define RS      164
#define OFF_C   64
#define OFF_DEC 128
#define OFF_XW  144
#define OFF_OB  160

// ---------- DPP wave-64 sum (result valid in lane 63) ----------
template <int CTRL>
__device__ __forceinline__ float dpp_add(float x) {
    int y = __builtin_amdgcn_update_dpp(0, __float_as_int(x), CTRL, 0xF, 0xF, true);
    return x + __int_as_float(y);
}
__device__ __forceinline__ float wave_sum_lane63(float x) {
    x = dpp_add<0x111>(x);
    x = dpp_add<0x112>(x);
    x = dpp_add<0x114>(x);
    x = dpp_add<0x118>(x);
    x = dpp_add<0x142>(x);
    x = dpp_add<0x143>(x);
    return x;
}

__device__ __forceinline__ float softplusf(float z) {
    return (z > 20.f) ? z : log1pf(expf(z));
}

// ---------- duplicate q -> logits (tier-3 only) ----------
__global__ void dup_q(float* __restrict__ q) {
    int i = blockIdx.x * 256 + threadIdx.x;
    if (i < TB) q[TB + i] = q[i];
}

// ---------- init (8 blocks): Wproj[64][16] and g0[16][64] ----------
__global__ __launch_bounds__(256)
void init_proj2(const float* __restrict__ Win, const float* __restrict__ Wout,
                const float* __restrict__ initS,
                float* __restrict__ wproj, float* __restrict__ g0) {
    const int t = threadIdx.x;
    if (blockIdx.x < 4) {
        const int idx = blockIdx.x * 256 + t;      // 0..1023
        const int k = idx >> 4, h = idx & 15;
        float s = 0.f;
#pragma unroll 8
        for (int p = 0; p < PDIM; ++p)
            s = fmaf(Win[(size_t)k * DINN + h * 64 + p], Wout[h * 64 + p], s);
        wproj[idx] = s;   // [k][h]
    } else {
        const int idx = (blockIdx.x - 4) * 256 + t; // 0..1023
        const int h = idx >> 6, n = idx & 63;
        float s = 0.f;
#pragma unroll 8
        for (int p = 0; p < PDIM; ++p)
            s = fmaf(initS[h * PDIM * NSTATE + p * NSTATE + n], Wout[h * 64 + p], s);
        g0[idx] = s;      // [h][n]
    }
}

// ---------- prelude2 v2: LDS-staged obs, broadcast ds_reads ----------
// block = 256 thr = 4 waves; block handles 32 rows (8 per wave)
__global__ __launch_bounds__(256)
void prelude2(const float* __restrict__ obs, const float* __restrict__ reward,
              const float* __restrict__ WB, const float* __restrict__ WC,
              const float* __restrict__ Wdt, const float* __restrict__ dtb,
              const float* __restrict__ Alog, const float* __restrict__ Dv,
              const float* __restrict__ wproj, float* __restrict__ rows) {
    __shared__ float lds[4][64][10];   // [wave][k][row] pad-10

    const int t    = threadIdx.x;
    const int lane = t & 63;
    const int wv   = t >> 6;
    const int row0b = blockIdx.x * 32;

    // stage obs: 2 float4 per thread, coalesced; wave-local writes
    {
        const float4* op4 = (const float4*)(obs + (size_t)row0b * OBSD) + t * 2;
        float4 v0 = op4[0], v1 = op4[1];
        const int rb = t >> 3;          // row-in-block 0..31 (rb>>3 == wv)
        const int r  = rb & 7;
        const int c0 = (t & 7) * 8;
        lds[wv][c0 + 0][r] = v0.x; lds[wv][c0 + 1][r] = v0.y;
        lds[wv][c0 + 2][r] = v0.z; lds[wv][c0 + 3][r] = v0.w;
        lds[wv][c0 + 4][r] = v1.x; lds[wv][c0 + 5][r] = v1.y;
        lds[wv][c0 + 6][r] = v1.z; lds[wv][c0 + 7][r] = v1.w;
    }
    // same-wave LDS writes are visible to later reads in program order; no barrier.

    const int row0 = row0b + wv * 8;
    const int h = lane & 15;
    const int q = lane >> 4;

    const float wdt_h = Wdt[h];
    const float dtb_h = dtb[h];
    const float A_h   = -expf(Alog[h]);
    const float D_h   = Dv[h];
    float wpj[16];
#pragma unroll
    for (int j = 0; j < 16; ++j)
        wpj[j] = wproj[(q * 16 + j) * 16 + h];

    float aB[8], aC[8];
#pragma unroll
    for (int r = 0; r < 8; ++r) { aB[r] = 0.f; aC[r] = 0.f; }

    const float* base = &lds[wv][0][0];
#pragma unroll 4
    for (int kk = 0; kk < OBSD; ++kk) {
        const float2* pr = (const float2*)(base + kk * 10);
        float2 p0 = pr[0], p1 = pr[1], p2 = pr[2], p3 = pr[3];  // rows 0..7 (broadcast)
        float wb = WB[kk * 64 + lane];
        float wc = WC[kk * 64 + lane];
        aB[0] = fmaf(p0.x, wb, aB[0]);  aC[0] = fmaf(p0.x, wc, aC[0]);
        aB[1] = fmaf(p0.y, wb, aB[1]);  aC[1] = fmaf(p0.y, wc, aC[1]);
        aB[2] = fmaf(p1.x, wb, aB[2]);  aC[2] = fmaf(p1.x, wc, aC[2]);
        aB[3] = fmaf(p1.y, wb, aB[3]);  aC[3] = fmaf(p1.y, wc, aC[3]);
        aB[4] = fmaf(p2.x, wb, aB[4]);  aC[4] = fmaf(p2.x, wc, aC[4]);
        aB[5] = fmaf(p2.y, wb, aB[5]);  aC[5] = fmaf(p2.y, wc, aC[5]);
        aB[6] = fmaf(p3.x, wb, aB[6]);  aC[6] = fmaf(p3.x, wc, aC[6]);
        aB[7] = fmaf(p3.y, wb, aB[7]);  aC[7] = fmaf(p3.y, wc, aC[7]);
    }

#pragma unroll 1
    for (int r = 0; r < 8; ++r) {
        const int row = row0 + r;
        float* rb = rows + (size_t)row * RS;
        rb[lane]         = aB[r];
        rb[OFF_C + lane] = aC[r];

        // w[h] partial over this lane's k-quarter (obs L1-hot)
        const float4* oq = (const float4*)(obs + (size_t)row * OBSD + q * 16);
        float4 o0 = oq[0], o1 = oq[1], o2 = oq[2], o3 = oq[3];
        float wpart = 0.f;
        wpart = fmaf(o0.x, wpj[0],  wpart); wpart = fmaf(o0.y, wpj[1],  wpart);
        wpart = fmaf(o0.z, wpj[2],  wpart); wpart = fmaf(o0.w, wpj[3],  wpart);
        wpart = fmaf(o1.x, wpj[4],  wpart); wpart = fmaf(o1.y, wpj[5],  wpart);
        wpart = fmaf(o1.z, wpj[6],  wpart); wpart = fmaf(o1.w, wpj[7],  wpart);
        wpart = fmaf(o2.x, wpj[8],  wpart); wpart = fmaf(o2.y, wpj[9],  wpart);
        wpart = fmaf(o2.z, wpj[10], wpart); wpart = fmaf(o2.w, wpj[11], wpart);
        wpart = fmaf(o3.x, wpj[12], wpart); wpart = fmaf(o3.y, wpj[13], wpart);
        wpart = fmaf(o3.z, wpj[14], wpart); wpart = fmaf(o3.w, wpj[15], wpart);
        wpart += __shfl_xor(wpart, 16, 64);
        wpart += __shfl_xor(wpart, 32, 64);

        const float rew  = reward[row];
        const float dtv  = softplusf(fmaf(rew, wdt_h, dtb_h));
        const float decv = expf(dtv * A_h);
        const float xwv  = dtv * wpart;
        if (q == 0) rb[OFF_DEC + h] = decv;
        if (q == 1) rb[OFF_XW  + h] = xwv;

        float dw = D_h * wpart;
        dw += __shfl_xor(dw, 1, 64);
        dw += __shfl_xor(dw, 2, 64);
        dw += __shfl_xor(dw, 4, 64);
        dw += __shfl_xor(dw, 8, 64);
        if (lane == 0) rb[OFF_OB] = dw;
    }
}

// helper: load 32 uniform floats (dec|xw) into two statically-indexed arrays
#define LOAD_DX(ptr, dd, xx)                                              \
    {                                                                     \
        const float4* _p = (const float4*)((ptr) + OFF_DEC);              \
        float4 a0 = _p[0], a1 = _p[1], a2 = _p[2], a3 = _p[3];            \
        float4 b0 = _p[4], b1 = _p[5], b2 = _p[6], b3 = _p[7];            \
        dd[0]=a0.x; dd[1]=a0.y; dd[2]=a0.z; dd[3]=a0.w;                   \
        dd[4]=a1.x; dd[5]=a1.y; dd[6]=a1.z; dd[7]=a1.w;                   \
        dd[8]=a2.x; dd[9]=a2.y; dd[10]=a2.z; dd[11]=a2.w;                 \
        dd[12]=a3.x; dd[13]=a3.y; dd[14]=a3.z; dd[15]=a3.w;               \
        xx[0]=b0.x; xx[1]=b0.y; xx[2]=b0.z; xx[3]=b0.w;                   \
        xx[4]=b1.x; xx[5]=b1.y; xx[6]=b1.z; xx[7]=b1.w;                   \
        xx[8]=b2.x; xx[9]=b2.y; xx[10]=b2.z; xx[11]=b2.w;                 \
        xx[12]=b3.x; xx[13]=b3.y; xx[14]=b3.z; xx[15]=b3.w;               \
    }

// ---------- phase A: per-(b,c) zero-init chunk scan -> Send, Ptot ----------
template <int CL>
__global__ __launch_bounds__(256)
void phaseA(const float* __restrict__ rows, float* __restrict__ Send,
            float* __restrict__ Ptot) {
    int w = blockIdx.x * 4 + (threadIdx.x >> 6);
    w = __builtin_amdgcn_readfirstlane(w);
    const int lane = threadIdx.x & 63;   // n
    const int b = w & 63;
    const int c = w >> 6;

    const float* rowp = rows + ((size_t)(c * CL) * BKK + b) * RS;
    float g[16], Pc[16];
#pragma unroll
    for (int hh = 0; hh < 16; ++hh) { g[hh] = 0.f; Pc[hh] = 1.f; }

    float Bv = rowp[lane];
    float dec_[16], xw_[16];
    LOAD_DX(rowp, dec_, xw_);

#pragma unroll 2
    for (int i = 0; i < CL; ++i) {
        const float* nxt = rowp + (size_t)RS * BKK;
        float Bn = 0.f;
        float decn_[16], xwn_[16];
        if (i < CL - 1) {
            Bn = nxt[lane];
            LOAD_DX(nxt, decn_, xwn_);
        }
#pragma unroll
        for (int hh = 0; hh < 16; ++hh) {
            g[hh] = fmaf(g[hh], dec_[hh], xw_[hh] * Bv);
            Pc[hh] *= dec_[hh];
        }
        rowp = nxt; Bv = Bn;
        if (i < CL - 1) {
#pragma unroll
            for (int hh = 0; hh < 16; ++hh) { dec_[hh] = decn_[hh]; xw_[hh] = xwn_[hh]; }
        }
    }

    const size_t base = ((size_t)c * BKK + b) * 16;
#pragma unroll
    for (int hh = 0; hh < 16; ++hh)
        Send[(base + hh) * 64 + lane] = g[hh];
    if (lane == 0) {
#pragma unroll
        for (int hh = 0; hh < 16; ++hh)
            Ptot[base + hh] = Pc[hh];
    }
}

// ---------- phase B: serial scan over NC chunk states (per b), prefetched ----------
template <int CL>
__global__ __launch_bounds__(64)
void phaseB(const float* __restrict__ g0, const float* __restrict__ Send,
            const float* __restrict__ Ptot, float* __restrict__ gcbuf) {
    const int NCv  = TT / CL;
    const int b    = blockIdx.x;
    const int lane = threadIdx.x;   // n

    float g[16];
#pragma unroll
    for (int hh = 0; hh < 16; ++hh)
        g[hh] = g0[hh * 64 + lane];

    // preload chunk 0 combine data
    float S_[16], P_[16];
    {
        const size_t base = (size_t)b * 16;
#pragma unroll
        for (int hh = 0; hh < 16; ++hh) S_[hh] = Send[(base + hh) * 64 + lane];
        const float4* pp = (const float4*)(Ptot + base);
        float4 a0 = pp[0], a1 = pp[1], a2 = pp[2], a3 = pp[3];
        P_[0]=a0.x; P_[1]=a0.y; P_[2]=a0.z; P_[3]=a0.w;
        P_[4]=a1.x; P_[5]=a1.y; P_[6]=a1.z; P_[7]=a1.w;
        P_[8]=a2.x; P_[9]=a2.y; P_[10]=a2.z; P_[11]=a2.w;
        P_[12]=a3.x; P_[13]=a3.y; P_[14]=a3.z; P_[15]=a3.w;
    }

#pragma unroll 1
    for (int c = 0; c < NCv; ++c) {
        const size_t base  = ((size_t)c * BKK + b) * 16;
        float Sn[16], Pn[16];
        if (c < NCv - 1) {
            const size_t nb = ((size_t)(c + 1) * BKK + b) * 16;
#pragma unroll
            for (int hh = 0; hh < 16; ++hh) Sn[hh] = Send[(nb + hh) * 64 + lane];
            const float4* pp = (const float4*)(Ptot + nb);
            float4 a0 = pp[0], a1 = pp[1], a2 = pp[2], a3 = pp[3];
            Pn[0]=a0.x; Pn[1]=a0.y; Pn[2]=a0.z; Pn[3]=a0.w;
            Pn[4]=a1.x; Pn[5]=a1.y; Pn[6]=a1.z; Pn[7]=a1.w;
            Pn[8]=a2.x; Pn[9]=a2.y; Pn[10]=a2.z; Pn[11]=a2.w;
            Pn[12]=a3.x; Pn[13]=a3.y; Pn[14]=a3.z; Pn[15]=a3.w;
        }
#pragma unroll
        for (int hh = 0; hh < 16; ++hh)
            gcbuf[(base + hh) * 64 + lane] = g[hh];
        if (c < NCv - 1) {
#pragma unroll
            for (int hh = 0; hh < 16; ++hh) {
                g[hh] = fmaf(P_[hh], g[hh], S_[hh]);
                P_[hh] = Pn[hh]; S_[hh] = Sn[hh];
            }
        }
    }
}

// ---------- phase C: per-(b,c) seeded chunk scan -> q AND logits ----------
template <int CL>
__global__ __launch_bounds__(256)
void phaseC(const float* __restrict__ rows, const float* __restrict__ gcbuf,
            float* __restrict__ qout) {
    int w = blockIdx.x * 4 + (threadIdx.x >> 6);
    w = __builtin_amdgcn_readfirstlane(w);
    const int lane = threadIdx.x & 63;   // n
    const int b = w & 63;
    const int c = w >> 6;

    const size_t sbase = ((size_t)c * BKK + b) * 16;
    float g[16];
#pragma unroll
    for (int hh = 0; hh < 16; ++hh)
        g[hh] = gcbuf[(sbase + hh) * 64 + lane];

    const float* rowp = rows + ((size_t)(c * CL) * BKK + b) * RS;
    float Bv = rowp[lane];
    float Cv = rowp[OFF_C + lane];
    float ob = rowp[OFF_OB];
    float dec_[16], xw_[16];
    LOAD_DX(rowp, dec_, xw_);

#pragma unroll 2
    for (int i = 0; i < CL; ++i) {
        const float* nxt = rowp + (size_t)RS * BKK;
        float Bn = 0.f, Cn = 0.f, obn = 0.f;
        float decn_[16], xwn_[16];
        if (i < CL - 1) {
            Bn = nxt[lane]; Cn = nxt[OFF_C + lane]; obn = nxt[OFF_OB];
            LOAD_DX(nxt, decn_, xwn_);
        }

        float y = 0.f;
#pragma unroll
        for (int hh = 0; hh < 16; ++hh) {
            g[hh] = fmaf(g[hh], dec_[hh], xw_[hh] * Bv);
            y = fmaf(g[hh], Cv, y);
        }

        float tot = wave_sum_lane63(y);
        if (lane == 63) {
            const size_t idx = (size_t)(c * CL + i) * BKK + b;
            const float v = tot + ob;
            qout[idx]      = v;   // q
            qout[TB + idx] = v;   // logits
        }

        rowp = nxt; Bv = Bn; Cv = Cn; ob = obn;
        if (i < CL - 1) {
#pragma unroll
            for (int hh = 0; hh < 16; ++hh) { dec_[hh] = decn_[hh]; xw_[hh] = xwn_[hh]; }
        }
    }
}

// ---------- tier-3: scan3 (R7 path, validated) ----------
__global__ __launch_bounds__(64)
void scan3_kernel(const float* __restrict__ rows, const float* __restrict__ g0,
                  float* __restrict__ qout) {
    const int b    = blockIdx.x;
    const int lane = threadIdx.x;   // n

    float g[16];
#pragma unroll
    for (int hh = 0; hh < 16; ++hh)
        g[hh] = g0[hh * 64 + lane];

    const float* rowp = rows + (size_t)b * RS;
    float Bv = rowp[lane];
    float Cv = rowp[OFF_C + lane];

#pragma unroll 2
    for (int t = 0; t < TT; ++t) {
        const float* nrow = rowp + (size_t)RS * BKK;
        float Bn = 0.f, Cn = 0.f;
        if (t < TT - 1) { Bn = nrow[lane]; Cn = nrow[OFF_C + lane]; }

        float y = 0.f;
#pragma unroll
        for (int hh = 0; hh < 16; ++hh) {
            float tmp = rowp[OFF_XW + hh] * Bv;
            g[hh] = fmaf(g[hh], rowp[OFF_DEC + hh], tmp);
            y = fmaf(g[hh], Cv, y);
        }
        const float ob = rowp[OFF_OB];

        float tot = wave_sum_lane63(y);
        if (lane == 63) qout[(size_t)t * BKK + b] = tot + ob;

        rowp = nrow; Bv = Bn; Cv = Cn;
    }
}

extern "C" void kernel_launch(void* const* d_in, const int* in_sizes, int n_in,
                              void* d_out, int out_size, void* d_ws, size_t ws_size,
                              hipStream_t stream) {
    const float* obs    = (const float*)d_in[0];
    const float* reward = (const float*)d_in[1];
    const float* Win    = (const float*)d_in[2];
    const float* WB     = (const float*)d_in[3];
    const float* WC     = (const float*)d_in[4];
    const float* Wdt    = (const float*)d_in[5];
    const float* dtb    = (const float*)d_in[6];
    const float* Alog   = (const float*)d_in[7];
    const float* Dv     = (const float*)d_in[8];
    const float* Wout   = (const float*)d_in[9];
    const float* initS  = (const float*)d_in[10];
    float* qout = (float*)d_out;

    const size_t n_rows = (size_t)TB * RS;    // 21.5 M floats (86.0 MB)

    float* rows  = (float*)d_ws;
    float* wproj = rows + n_rows;
    float* g0    = wproj + 1024;

    // tier sizes
    const size_t n_cs64 = (size_t)64 * BKK * 16 * 64;  // 4.19 M floats
    const size_t n_pt64 = (size_t)64 * BKK * 16;
    const size_t need64 = (n_rows + 2048 + 2 * n_cs64 + n_pt64) * 4;   // ~119.9 MB

    const size_t n_cs32 = (size_t)32 * BKK * 16 * 64;  // 2.10 M floats
    const size_t n_pt32 = (size_t)32 * BKK * 16;
    const size_t need32 = (n_rows + 2048 + 2 * n_cs32 + n_pt32) * 4;   // ~102.9 MB

    init_proj2<<<dim3(8), dim3(256), 0, stream>>>(Win, Wout, initS, wproj, g0);
    prelude2<<<dim3(TB / 32), dim3(256), 0, stream>>>(obs, reward, WB, WC, Wdt,
                                                      dtb, Alog, Dv, wproj, rows);

    if (ws_size >= need64) {
        float* Send  = g0 + 1024;
        float* gcbuf = Send + n_cs64;
        float* Ptot  = gcbuf + n_cs64;
        phaseA<32><<<dim3(64 * 16), dim3(256), 0, stream>>>(rows, Send, Ptot);
        phaseB<32><<<dim3(BKK), dim3(64), 0, stream>>>(g0, Send, Ptot, gcbuf);
        phaseC<32><<<dim3(64 * 16), dim3(256), 0, stream>>>(rows, gcbuf, qout);
    } else if (ws_size >= need32) {
        float* Send  = g0 + 1024;
        float* gcbuf = Send + n_cs32;
        float* Ptot  = gcbuf + n_cs32;
        phaseA<64><<<dim3(32 * 16), dim3(256), 0, stream>>>(rows, Send, Ptot);
        phaseB<64><<<dim3(BKK), dim3(64), 0, stream>>>(g0, Send, Ptot, gcbuf);
        phaseC<64><<<dim3(32 * 16), dim3(256), 0, stream>>>(rows, gcbuf, qout);
    } else {
        scan3_kernel<<<dim3(BKK), dim3(64), 0, stream>>>(rows, g0, qout);
        dup_q<<<dim3(TB / 256), dim3(256), 0, stream>>>(qout);
    }
}